// Round 1
// baseline (230.149 us; speedup 1.0000x reference)
//
#include <hip/hip_runtime.h>
#include <hip/hip_bf16.h>
#include <stdint.h>

// MultiHeadSelfAttention (b=2,t=2048,m=1024,h=16,d=64), bf16 MFMA pipeline.
// Key structural facts exploited:
//  - reference splits heads by reshape (NOT transpose): head h = contiguous
//    rows [128h,128h+128) of the per-batch (2048x1024) projection, viewed (2048x64).
//  - RoPE uses the SAME angle for every token (indexed by scalar t=seq_len);
//    a shared orthogonal rotation of q and k leaves q.k^T exactly invariant,
//    and v/o are unrotated => RoPE is a no-op on the output. Skipped.

typedef __attribute__((ext_vector_type(8))) short bf16x8;
typedef __attribute__((ext_vector_type(4))) float f32x4;

__device__ inline unsigned short f2b(float f) {
  union { float f; unsigned int u; } x; x.f = f;
  unsigned int r = x.u + 0x7fffu + ((x.u >> 16) & 1u);  // RTNE
  return (unsigned short)(r >> 16);
}

__global__ __launch_bounds__(256) void cvt_kernel(const float* __restrict__ in,
                                                  unsigned short* __restrict__ out, int n4) {
  int i = blockIdx.x * 256 + threadIdx.x;
  if (i < n4) {
    float4 v = reinterpret_cast<const float4*>(in)[i];
    ushort4 o;
    o.x = f2b(v.x); o.y = f2b(v.y); o.z = f2b(v.z); o.w = f2b(v.w);
    reinterpret_cast<ushort4*>(out)[i] = o;
  }
}

// C(MxN) = A(MxK) @ W(NxK)^T + bias.  128x128 tile, BK=64, 4 waves (each 64x64).
// LDS staged via global_load_lds(16B) with XOR-swizzled global source so that
// ds_read_b128 fragment reads are bank-conflict-light (rows stride 128B).
// EPI=0: z selects {Wq,Wk,Wv}, bf16 output. EPI=1: fp32 output (final proj).
template<int EPI>
__global__ __launch_bounds__(256) void gemm_bt(
    const unsigned short* __restrict__ A,
    const unsigned short* __restrict__ W0, const unsigned short* __restrict__ W1,
    const unsigned short* __restrict__ W2,
    const float* __restrict__ b0, const float* __restrict__ b1, const float* __restrict__ b2,
    unsigned short* __restrict__ o0, unsigned short* __restrict__ o1,
    unsigned short* __restrict__ o2,
    float* __restrict__ of, int M, int N, int K)
{
  const int tid = threadIdx.x;
  const int lane = tid & 63;
  const int wid = tid >> 6;
  const int q4 = lane >> 4;
  const int l15 = lane & 15;
  const int wr = wid >> 1, wc = wid & 1;

  const unsigned short* W = W0; const float* bias = b0; unsigned short* ob = o0;
  if (EPI == 0) {
    if (blockIdx.z == 1) { W = W1; bias = b1; ob = o1; }
    else if (blockIdx.z == 2) { W = W2; bias = b2; ob = o2; }
  }

  __shared__ __align__(16) unsigned short sA[128 * 64];
  __shared__ __align__(16) unsigned short sB[128 * 64];

  f32x4 acc[4][4];
#pragma unroll
  for (int i = 0; i < 4; ++i)
#pragma unroll
    for (int j = 0; j < 4; ++j) acc[i][j] = (f32x4){0.f, 0.f, 0.f, 0.f};

  const size_t rowA0 = (size_t)blockIdx.x * 128;
  const size_t rowB0 = (size_t)blockIdx.y * 128;

  for (int k0 = 0; k0 < K; k0 += 64) {
    __syncthreads();  // prev-iter LDS reads done before overwrite
#pragma unroll
    for (int it = 0; it < 4; ++it) {
      int Loff = it * 4096 + wid * 1024;          // wave-uniform LDS byte base
      int L = Loff + lane * 16;                   // linear LDS byte this lane fills
      int row = L >> 7;                           // tile row (128B per row)
      int csrc = ((L >> 4) & 7) ^ (row & 7);      // inverse-swizzled source chunk
      const unsigned short* ga = A + (rowA0 + row) * K + k0 + csrc * 8;
      const unsigned short* gw = W + (rowB0 + row) * K + k0 + csrc * 8;
      __builtin_amdgcn_global_load_lds((const __attribute__((address_space(1))) void*)ga,
                                       (__attribute__((address_space(3))) void*)((char*)sA + Loff),
                                       16, 0, 0);
      __builtin_amdgcn_global_load_lds((const __attribute__((address_space(1))) void*)gw,
                                       (__attribute__((address_space(3))) void*)((char*)sB + Loff),
                                       16, 0, 0);
    }
    __syncthreads();  // drains vmcnt

#pragma unroll
    for (int ks = 0; ks < 2; ++ks) {
      bf16x8 af[4], bfr[4];
#pragma unroll
      for (int f = 0; f < 4; ++f) {
        int ra = wr * 64 + f * 16 + l15;
        af[f] = *(const bf16x8*)((const char*)sA + ra * 128 + ((ks * 64 + q4 * 16) ^ ((ra & 7) << 4)));
        int rb = wc * 64 + f * 16 + l15;
        bfr[f] = *(const bf16x8*)((const char*)sB + rb * 128 + ((ks * 64 + q4 * 16) ^ ((rb & 7) << 4)));
      }
#pragma unroll
      for (int i = 0; i < 4; ++i)
#pragma unroll
        for (int j = 0; j < 4; ++j)
          acc[i][j] = __builtin_amdgcn_mfma_f32_16x16x32_bf16(af[i], bfr[j], acc[i][j], 0, 0, 0);
    }
  }

  // epilogue: C row = base + q4*4 + r, col = base + l15 (m89 layout)
#pragma unroll
  for (int i = 0; i < 4; ++i) {
    int row = (int)rowA0 + wr * 64 + i * 16 + q4 * 4;
#pragma unroll
    for (int j = 0; j < 4; ++j) {
      int col = (int)rowB0 + wc * 64 + j * 16 + l15;
      float bv = bias[col];
#pragma unroll
      for (int r = 0; r < 4; ++r) {
        float v = acc[i][j][r] + bv;
        if (EPI == 0) ob[(size_t)(row + r) * N + col] = f2b(v);
        else          of[(size_t)(row + r) * N + col] = v;
      }
    }
  }
}

// Flash attention over one (b,h) head block: Q/K/V are contiguous (2048x64)
// bf16 row-major. Block = 128 Q-rows, 4 waves x 32 rows; KV tiles of 64.
__global__ __launch_bounds__(256) void attn_kernel(
    const unsigned short* __restrict__ Qg,
    const unsigned short* __restrict__ Kg,
    const unsigned short* __restrict__ Vg,
    unsigned short* __restrict__ ctx)
{
  const int tid = threadIdx.x;
  const int lane = tid & 63;
  const int wid = tid >> 6;
  const int q4 = lane >> 4;
  const int l15 = lane & 15;

  const int bh = blockIdx.y;
  const int b = bh >> 4, h = bh & 15;
  const size_t base = (size_t)b * 2097152 + (size_t)h * 131072;
  const unsigned short* Qh = Qg + base;
  const unsigned short* Kh = Kg + base;
  const unsigned short* Vh = Vg + base;
  const int q0 = blockIdx.x * 128;

  __shared__ __align__(16) unsigned short sK[64 * 64];     // swizzled linear
  __shared__ __align__(16) unsigned short sVT[64 * 72];    // V^T, padded stride 72
  __shared__ __align__(16) unsigned short sP[4][32 * 72];  // per-wave P, stride 72

  // Q fragments in registers (read once; rows = q0 + wid*32 + fm*16 + l15)
  bf16x8 qf[2][2];
#pragma unroll
  for (int fm = 0; fm < 2; ++fm)
#pragma unroll
    for (int ks = 0; ks < 2; ++ks) {
      int row = q0 + wid * 32 + fm * 16 + l15;
      qf[fm][ks] = *(const bf16x8*)(Qh + (size_t)row * 64 + ks * 32 + q4 * 8);
    }

  f32x4 oacc[2][4];
  float m_run[2][4], l_run[2][4];
#pragma unroll
  for (int fm = 0; fm < 2; ++fm) {
#pragma unroll
    for (int fn = 0; fn < 4; ++fn) oacc[fm][fn] = (f32x4){0.f, 0.f, 0.f, 0.f};
#pragma unroll
    for (int r = 0; r < 4; ++r) { m_run[fm][r] = -INFINITY; l_run[fm][r] = 0.f; }
  }

  for (int kv0 = 0; kv0 < 2048; kv0 += 64) {
    __syncthreads();  // prev-iter LDS consumers done
    // stage K tile (64x64, swizzled) via global_load_lds
#pragma unroll
    for (int it = 0; it < 2; ++it) {
      int Loff = it * 4096 + wid * 1024;
      int L = Loff + lane * 16;
      int row = L >> 7;
      int csrc = ((L >> 4) & 7) ^ (row & 7);
      const unsigned short* g = Kh + (size_t)(kv0 + row) * 64 + csrc * 8;
      __builtin_amdgcn_global_load_lds((const __attribute__((address_space(1))) void*)g,
                                       (__attribute__((address_space(3))) void*)((char*)sK + Loff),
                                       16, 0, 0);
    }
    // stage V transposed (reg -> ds_write, padded stride breaks bank conflicts)
    {
      int r0 = tid >> 3;
      int c0 = (tid & 7) * 8;
      uint4 va = *(const uint4*)(Vh + (size_t)(kv0 + r0) * 64 + c0);
      uint4 vb = *(const uint4*)(Vh + (size_t)(kv0 + r0 + 32) * 64 + c0);
      const unsigned short* pa = (const unsigned short*)&va;
      const unsigned short* pb = (const unsigned short*)&vb;
#pragma unroll
      for (int j = 0; j < 8; ++j) {
        sVT[(c0 + j) * 72 + r0] = pa[j];
        sVT[(c0 + j) * 72 + r0 + 32] = pb[j];
      }
    }
    __syncthreads();

    // S = Q K^T (per wave: 32x64)
    f32x4 sc[2][4];
#pragma unroll
    for (int fm = 0; fm < 2; ++fm)
#pragma unroll
      for (int fn = 0; fn < 4; ++fn) sc[fm][fn] = (f32x4){0.f, 0.f, 0.f, 0.f};
#pragma unroll
    for (int ks = 0; ks < 2; ++ks) {
      bf16x8 kf[4];
#pragma unroll
      for (int fn = 0; fn < 4; ++fn) {
        int rk = fn * 16 + l15;
        kf[fn] = *(const bf16x8*)((const char*)sK + rk * 128 + ((ks * 64 + q4 * 16) ^ ((rk & 7) << 4)));
      }
#pragma unroll
      for (int fm = 0; fm < 2; ++fm)
#pragma unroll
        for (int fn = 0; fn < 4; ++fn)
          sc[fm][fn] = __builtin_amdgcn_mfma_f32_16x16x32_bf16(qf[fm][ks], kf[fn], sc[fm][fn], 0, 0, 0);
    }

    // online softmax (fp32); row lives in 16 lanes of this lane's q4 group
#pragma unroll
    for (int fm = 0; fm < 2; ++fm) {
#pragma unroll
      for (int r = 0; r < 4; ++r) {
        float v0 = sc[fm][0][r] * 0.125f;
        float v1 = sc[fm][1][r] * 0.125f;
        float v2 = sc[fm][2][r] * 0.125f;
        float v3 = sc[fm][3][r] * 0.125f;
        float mx = fmaxf(fmaxf(v0, v1), fmaxf(v2, v3));
        mx = fmaxf(mx, __shfl_xor(mx, 1));
        mx = fmaxf(mx, __shfl_xor(mx, 2));
        mx = fmaxf(mx, __shfl_xor(mx, 4));
        mx = fmaxf(mx, __shfl_xor(mx, 8));
        float mold = m_run[fm][r];
        float mnew = fmaxf(mold, mx);
        float sc_o = __expf(mold - mnew);
        float p0 = __expf(v0 - mnew);
        float p1 = __expf(v1 - mnew);
        float p2 = __expf(v2 - mnew);
        float p3 = __expf(v3 - mnew);
        float rs = p0 + p1 + p2 + p3;
        rs += __shfl_xor(rs, 1);
        rs += __shfl_xor(rs, 2);
        rs += __shfl_xor(rs, 4);
        rs += __shfl_xor(rs, 8);
        l_run[fm][r] = l_run[fm][r] * sc_o + rs;
        m_run[fm][r] = mnew;
#pragma unroll
        for (int fn = 0; fn < 4; ++fn) oacc[fm][fn][r] *= sc_o;
        int rl = fm * 16 + q4 * 4 + r;
        sP[wid][rl * 72 +  0 + l15] = f2b(p0);
        sP[wid][rl * 72 + 16 + l15] = f2b(p1);
        sP[wid][rl * 72 + 32 + l15] = f2b(p2);
        sP[wid][rl * 72 + 48 + l15] = f2b(p3);
      }
    }
    __syncthreads();

    // O += P @ V   (A = P rows l15; B = V^T rows = output col d)
#pragma unroll
    for (int js = 0; js < 2; ++js) {
      bf16x8 pf[2], vf[4];
#pragma unroll
      for (int fm = 0; fm < 2; ++fm)
        pf[fm] = *(const bf16x8*)((const char*)&sP[wid][0] + (fm * 16 + l15) * 144 + js * 64 + q4 * 16);
#pragma unroll
      for (int fn = 0; fn < 4; ++fn)
        vf[fn] = *(const bf16x8*)((const char*)sVT + (fn * 16 + l15) * 144 + js * 64 + q4 * 16);
#pragma unroll
      for (int fm = 0; fm < 2; ++fm)
#pragma unroll
        for (int fn = 0; fn < 4; ++fn)
          oacc[fm][fn] = __builtin_amdgcn_mfma_f32_16x16x32_bf16(pf[fm], vf[fn], oacc[fm][fn], 0, 0, 0);
    }
  }

  // normalize + store to ctx[b, t_, h*64+d] (the o-transpose of the reference)
#pragma unroll
  for (int fm = 0; fm < 2; ++fm) {
#pragma unroll
    for (int r = 0; r < 4; ++r) {
      int trow = q0 + wid * 32 + fm * 16 + q4 * 4 + r;
      float inv = 1.0f / l_run[fm][r];
      size_t rowoff = ((size_t)b * 2048 + trow) * 1024 + h * 64;
#pragma unroll
      for (int fn = 0; fn < 4; ++fn)
        ctx[rowoff + fn * 16 + l15] = f2b(oacc[fm][fn][r] * inv);
    }
  }
}

extern "C" void kernel_launch(void* const* d_in, const int* in_sizes, int n_in,
                              void* d_out, int out_size, void* d_ws, size_t ws_size,
                              hipStream_t stream) {
  const float* x  = (const float*)d_in[0];
  const float* wq = (const float*)d_in[1];
  const float* bq = (const float*)d_in[2];
  const float* wk = (const float*)d_in[3];
  const float* bk = (const float*)d_in[4];
  const float* wv = (const float*)d_in[5];
  const float* bv = (const float*)d_in[6];
  const float* wo = (const float*)d_in[7];
  const float* bo = (const float*)d_in[8];
  // d_in[9]=rot_cos, d_in[10]=rot_sin: unused — constant-angle RoPE applied to
  // both q and k cancels exactly in q.k^T; v/o are unrotated.

  char* ws = (char*)d_ws;
  unsigned short* xb  = (unsigned short*)(ws);               // 8 MB (also ctx later)
  unsigned short* wqb = (unsigned short*)(ws + 8388608);     // 2 MB
  unsigned short* wkb = (unsigned short*)(ws + 10485760);
  unsigned short* wvb = (unsigned short*)(ws + 12582912);
  unsigned short* wob = (unsigned short*)(ws + 14680064);
  unsigned short* Qb  = (unsigned short*)(ws + 16777216);    // 8 MB
  unsigned short* Kb  = (unsigned short*)(ws + 25165824);    // 8 MB
  unsigned short* Vb  = (unsigned short*)(ws + 33554432);    // 8 MB
  unsigned short* ctx = xb;  // x is dead after the QKV projection

  cvt_kernel<<<4096, 256, 0, stream>>>(x,  xb,  1048576);
  cvt_kernel<<<1024, 256, 0, stream>>>(wq, wqb, 262144);
  cvt_kernel<<<1024, 256, 0, stream>>>(wk, wkb, 262144);
  cvt_kernel<<<1024, 256, 0, stream>>>(wv, wvb, 262144);
  cvt_kernel<<<1024, 256, 0, stream>>>(wo, wob, 262144);

  gemm_bt<0><<<dim3(32, 8, 3), 256, 0, stream>>>(
      xb, wqb, wkb, wvb, bq, bk, bv, Qb, Kb, Vb, nullptr, 4096, 1024, 1024);

  attn_kernel<<<dim3(16, 32), 256, 0, stream>>>(Qb, Kb, Vb, ctx);

  gemm_bt<1><<<dim3(32, 8, 1), 256, 0, stream>>>(
      ctx, wob, wob, wob, bo, bo, bo, nullptr, nullptr, nullptr,
      (float*)d_out, 4096, 1024, 1024);
}

// Round 3
// 171.783 us; speedup vs baseline: 1.3398x; 1.3398x over previous
//
#include <hip/hip_runtime.h>
#include <hip/hip_bf16.h>
#include <stdint.h>

// MultiHeadSelfAttention (b=2,t=2048,m=1024,h=16,d=64), bf16 MFMA pipeline.
//  - reshape head-split => head h = contiguous 131072-elem slab of the per-batch
//    (2048x1024) projection, viewed [2048][64] row-major.
//  - constant-angle RoPE on q,k cancels exactly in q.k^T => skipped.

typedef __attribute__((ext_vector_type(8))) short bf16x8;
typedef bf16x8 __attribute__((may_alias)) bf16x8_a;
typedef __attribute__((ext_vector_type(4))) float f32x4;
typedef __attribute__((ext_vector_type(2))) unsigned int u32x2;
typedef u32x2 __attribute__((may_alias)) u32x2_a;

__device__ inline unsigned short f2b(float f) {
  union { float f; unsigned int u; } x; x.f = f;
  unsigned int r = x.u + 0x7fffu + ((x.u >> 16) & 1u);  // RTNE
  return (unsigned short)(r >> 16);
}

__global__ __launch_bounds__(256) void cvt_kernel(const float* __restrict__ in,
                                                  unsigned short* __restrict__ out, int n4) {
  int i = blockIdx.x * 256 + threadIdx.x;
  if (i < n4) {
    float4 v = reinterpret_cast<const float4*>(in)[i];
    ushort4 o;
    o.x = f2b(v.x); o.y = f2b(v.y); o.z = f2b(v.z); o.w = f2b(v.w);
    reinterpret_cast<ushort4*>(out)[i] = o;
  }
}

__global__ __launch_bounds__(256) void cvt4_kernel(
    const float* __restrict__ a0, const float* __restrict__ a1,
    const float* __restrict__ a2, const float* __restrict__ a3,
    unsigned short* __restrict__ o0, unsigned short* __restrict__ o1,
    unsigned short* __restrict__ o2, unsigned short* __restrict__ o3, int n4) {
  const float* in = a0; unsigned short* out = o0;
  if (blockIdx.y == 1) { in = a1; out = o1; }
  else if (blockIdx.y == 2) { in = a2; out = o2; }
  else if (blockIdx.y == 3) { in = a3; out = o3; }
  int i = blockIdx.x * 256 + threadIdx.x;
  if (i < n4) {
    float4 v = reinterpret_cast<const float4*>(in)[i];
    ushort4 o;
    o.x = f2b(v.x); o.y = f2b(v.y); o.z = f2b(v.z); o.w = f2b(v.w);
    reinterpret_cast<ushort4*>(out)[i] = o;
  }
}

// C(MxN) = A(MxK) @ W(NxK)^T + bias.  128x128 tile, BK=64, 4 waves (each 64x64).
// EPI=0: z selects {Wq,Wk,Wv}; q,k written [token][n] bf16; V written HEAD-TRANSPOSED:
//   u = t*16 + (col>>6); VT[(b*16 + (u>>11))*131072 + (col&63)*2048 + (u&2047)]
// EPI=1: fp32 output (final projection).
template<int EPI>
__global__ __launch_bounds__(256) void gemm_bt(
    const unsigned short* __restrict__ A,
    const unsigned short* __restrict__ W0, const unsigned short* __restrict__ W1,
    const unsigned short* __restrict__ W2,
    const float* __restrict__ b0, const float* __restrict__ b1, const float* __restrict__ b2,
    unsigned short* __restrict__ o0, unsigned short* __restrict__ o1,
    unsigned short* __restrict__ o2,
    float* __restrict__ of, int M, int N, int K)
{
  const int tid = threadIdx.x;
  const int lane = tid & 63;
  const int wid = tid >> 6;
  const int q4 = lane >> 4;
  const int l15 = lane & 15;
  const int wr = wid >> 1, wc = wid & 1;

  const unsigned short* W = W0; const float* bias = b0; unsigned short* ob = o0;
  if (EPI == 0) {
    if (blockIdx.z == 1) { W = W1; bias = b1; ob = o1; }
    else if (blockIdx.z == 2) { W = W2; bias = b2; ob = o2; }
  }

  __shared__ __align__(16) unsigned short sA[128 * 64];
  __shared__ __align__(16) unsigned short sB[128 * 64];

  f32x4 acc[4][4];
#pragma unroll
  for (int i = 0; i < 4; ++i)
#pragma unroll
    for (int j = 0; j < 4; ++j) acc[i][j] = (f32x4){0.f, 0.f, 0.f, 0.f};

  const size_t rowA0 = (size_t)blockIdx.x * 128;
  const size_t rowB0 = (size_t)blockIdx.y * 128;

  for (int k0 = 0; k0 < K; k0 += 64) {
    __syncthreads();
#pragma unroll
    for (int it = 0; it < 4; ++it) {
      int Loff = it * 4096 + wid * 1024;
      int L = Loff + lane * 16;
      int row = L >> 7;
      int csrc = ((L >> 4) & 7) ^ (row & 7);
      const unsigned short* ga = A + (rowA0 + row) * K + k0 + csrc * 8;
      const unsigned short* gw = W + (rowB0 + row) * K + k0 + csrc * 8;
      __builtin_amdgcn_global_load_lds((const __attribute__((address_space(1))) void*)ga,
                                       (__attribute__((address_space(3))) void*)((char*)sA + Loff),
                                       16, 0, 0);
      __builtin_amdgcn_global_load_lds((const __attribute__((address_space(1))) void*)gw,
                                       (__attribute__((address_space(3))) void*)((char*)sB + Loff),
                                       16, 0, 0);
    }
    __syncthreads();

#pragma unroll
    for (int ks = 0; ks < 2; ++ks) {
      bf16x8 af[4], bfr[4];
#pragma unroll
      for (int f = 0; f < 4; ++f) {
        int ra = wr * 64 + f * 16 + l15;
        af[f] = *(const bf16x8*)((const char*)sA + ra * 128 + ((ks * 64 + q4 * 16) ^ ((ra & 7) << 4)));
        int rb = wc * 64 + f * 16 + l15;
        bfr[f] = *(const bf16x8*)((const char*)sB + rb * 128 + ((ks * 64 + q4 * 16) ^ ((rb & 7) << 4)));
      }
#pragma unroll
      for (int i = 0; i < 4; ++i)
#pragma unroll
        for (int j = 0; j < 4; ++j)
          acc[i][j] = __builtin_amdgcn_mfma_f32_16x16x32_bf16(af[i], bfr[j], acc[i][j], 0, 0, 0);
    }
  }

#pragma unroll
  for (int i = 0; i < 4; ++i) {
    int row = (int)rowA0 + wr * 64 + i * 16 + q4 * 4;
#pragma unroll
    for (int j = 0; j < 4; ++j) {
      int col = (int)rowB0 + wc * 64 + j * 16 + l15;
      float bv = bias[col];
      if (EPI == 0 && blockIdx.z == 2) {
        // head-transposed V output
        int bb = row >> 11;
        int cb = col >> 6, dd = col & 63;
#pragma unroll
        for (int r = 0; r < 4; ++r) {
          int u = ((row + r) & 2047) * 16 + cb;      // head-seq index
          size_t a = ((size_t)(bb * 16 + (u >> 11))) * 131072 + (size_t)dd * 2048 + (u & 2047);
          ob[a] = f2b(acc[i][j][r] + bv);
        }
      } else {
#pragma unroll
        for (int r = 0; r < 4; ++r) {
          float v = acc[i][j][r] + bv;
          if (EPI == 0) ob[(size_t)(row + r) * N + col] = f2b(v);
          else          of[(size_t)(row + r) * N + col] = v;
        }
      }
    }
  }
}

// Flash attention, swapped-QK^T structure.
// Block = 512 thr (8 waves), 128 Q rows (16/wave), KV tiles of 64, dbuf K/VT.
// S^T = mfma(K, Q): lane(q4,l15) holds S[k=fm*16+q4*4+r][q=l15] -> row softmax
// in 2 shfl_xor. P through per-wave sP (fenced). V pre-transposed globally, so
// PV B-fragments read exactly like K fragments (XOR-swizzled ds_read_b128).
__global__ __launch_bounds__(512, 4) void attn_kernel(
    const unsigned short* __restrict__ Qg,
    const unsigned short* __restrict__ Kg,
    const unsigned short* __restrict__ VTg,
    unsigned short* __restrict__ ctx)
{
  const int tid = threadIdx.x;
  const int lane = tid & 63;
  const int wid = tid >> 6;
  const int q4 = lane >> 4;
  const int l15 = lane & 15;

  // XCD-aware decode: xcd = bid&7 owns 4 whole heads -> K/VT L2-resident.
  const int bid = blockIdx.x;
  const int bh = (bid & 7) * 4 + ((bid >> 3) >> 4);
  const int qt = (bid >> 3) & 15;
  const int b = bh >> 4, h = bh & 15;
  const size_t base = (size_t)bh * 131072;
  const unsigned short* Qh = Qg + base;
  const unsigned short* Kh = Kg + base;
  const unsigned short* VTh = VTg + base;
  const int q0 = qt * 128;

  __shared__ __align__(16) unsigned short sK[2][64 * 64];   // [kv][d], XOR-swizzled
  __shared__ __align__(16) unsigned short sV[2][64 * 64];   // [d][kv-seg], XOR-swizzled
  __shared__ __align__(16) unsigned short sP[8][1152];      // per-wave P[16 q][64 kv], stride 72

  // Q fragments (B-operand of swapped QK^T): B_T[n=q(=l15)][k=d]
  bf16x8 qf[2];
#pragma unroll
  for (int ks = 0; ks < 2; ++ks)
    qf[ks] = *(const bf16x8*)(Qh + (size_t)(q0 + wid * 16 + l15) * 64 + ks * 32 + q4 * 8);

  // staging sources (per-lane pre-swizzled; global_load_lds dest is linear)
  const int rK = tid >> 3;
  const int colK = ((tid & 7) ^ (rK & 7)) * 8;
  const unsigned short* gK = Kh + (size_t)rK * 64 + colK;      // + kv0*64
  const unsigned short* gV = VTh + (size_t)rK * 2048 + colK;   // + kv0
  char* sKc = (char*)sK;
  char* sVc = (char*)sV;
  char* sPw = (char*)sP + wid * 2304 + l15 * 144;

  auto stage = [&](int bs, int kv0) {
    __builtin_amdgcn_global_load_lds(
        (const __attribute__((address_space(1))) void*)(gK + (size_t)kv0 * 64),
        (__attribute__((address_space(3))) void*)(sKc + bs * 8192 + wid * 1024), 16, 0, 0);
    __builtin_amdgcn_global_load_lds(
        (const __attribute__((address_space(1))) void*)(gV + kv0),
        (__attribute__((address_space(3))) void*)(sVc + bs * 8192 + wid * 1024), 16, 0, 0);
  };

  f32x4 oacc[4];                       // O[q=q4*4+r][d=fn*16+l15]
#pragma unroll
  for (int fn = 0; fn < 4; ++fn) oacc[fn] = (f32x4){0.f, 0.f, 0.f, 0.f};
  float m_run = -INFINITY, l_run = 0.f;  // softmax state for q-row = l15

  stage(0, 0);

  for (int t = 0; t < 32; ++t) {
    const int cur = t & 1;
    __syncthreads();                   // drains vmcnt: tile t staged; buf cur^1 free
    if (t < 31) stage(cur ^ 1, (t + 1) * 64);

    // ---- S^T = K Q^T : sc[fm][r] = S[kv=fm*16+q4*4+r][q=l15]
    f32x4 sc[4];
#pragma unroll
    for (int fm = 0; fm < 4; ++fm) sc[fm] = (f32x4){0.f, 0.f, 0.f, 0.f};
    __builtin_amdgcn_s_setprio(1);
#pragma unroll
    for (int ks = 0; ks < 2; ++ks) {
#pragma unroll
      for (int fm = 0; fm < 4; ++fm) {
        const int rk = fm * 16 + l15;
        bf16x8_a kf = *(const bf16x8_a*)(sKc + cur * 8192 + rk * 128 +
                                         ((ks * 64 + q4 * 16) ^ ((rk & 7) << 4)));
        sc[fm] = __builtin_amdgcn_mfma_f32_16x16x32_bf16(kf, qf[ks], sc[fm], 0, 0, 0);
      }
    }
    __builtin_amdgcn_s_setprio(0);

    // ---- online softmax: 16 local values + 2 cross-q4 shuffles
    float mx = -INFINITY;
#pragma unroll
    for (int fm = 0; fm < 4; ++fm)
#pragma unroll
      for (int r = 0; r < 4; ++r) {
        sc[fm][r] *= 0.125f;           // 1/sqrt(64)
        mx = fmaxf(mx, sc[fm][r]);
      }
    mx = fmaxf(mx, __shfl_xor(mx, 16));
    mx = fmaxf(mx, __shfl_xor(mx, 32));
    const float mnew = fmaxf(m_run, mx);
    const float sc_o = __expf(m_run - mnew);
    float rs = 0.f;
#pragma unroll
    for (int fm = 0; fm < 4; ++fm)
#pragma unroll
      for (int r = 0; r < 4; ++r) {
        sc[fm][r] = __expf(sc[fm][r] - mnew);
        rs += sc[fm][r];
      }
    rs += __shfl_xor(rs, 16);
    rs += __shfl_xor(rs, 32);
    l_run = l_run * sc_o + rs;
    m_run = mnew;

    // ---- pack P -> sP[q=l15][kv] (4x ds_write_b64; kv = fm*16 + q4*4 + r)
#pragma unroll
    for (int fm = 0; fm < 4; ++fm) {
      u32x2 pk;
      pk[0] = (unsigned)f2b(sc[fm][0]) | ((unsigned)f2b(sc[fm][1]) << 16);
      pk[1] = (unsigned)f2b(sc[fm][2]) | ((unsigned)f2b(sc[fm][3]) << 16);
      *(u32x2_a*)(sPw + fm * 32 + q4 * 8) = pk;
    }
    // fence: cross-lane LDS exchange within the wave (writes above, reads below)
    asm volatile("s_waitcnt lgkmcnt(0)" ::: "memory");
    __builtin_amdgcn_sched_barrier(0);

    // ---- rescale O (state per q=l15; O rows q=q4*4+r -> broadcast within group)
#pragma unroll
    for (int r = 0; r < 4; ++r) {
      const float so = __shfl(sc_o, (lane & 48) | (q4 * 4 + r));
#pragma unroll
      for (int fn = 0; fn < 4; ++fn) oacc[fn][r] *= so;
    }

    // ---- O += P V : A from sP, B = VT rows (d), same swizzle as K
#pragma unroll
    for (int ks2 = 0; ks2 < 2; ++ks2) {
      bf16x8_a pfrag = *(const bf16x8_a*)(sPw + ks2 * 64 + q4 * 16);
      __builtin_amdgcn_s_setprio(1);
#pragma unroll
      for (int fn = 0; fn < 4; ++fn) {
        const int rv = fn * 16 + l15;
        bf16x8_a vf = *(const bf16x8_a*)(sVc + cur * 8192 + rv * 128 +
                                         ((ks2 * 64 + q4 * 16) ^ ((rv & 7) << 4)));
        oacc[fn] = __builtin_amdgcn_mfma_f32_16x16x32_bf16(pfrag, vf, oacc[fn], 0, 0, 0);
      }
      __builtin_amdgcn_s_setprio(0);
    }
  }

  // ---- normalize + store ctx[b, t, h*64+d]
  const float inv = 1.0f / l_run;
#pragma unroll
  for (int r = 0; r < 4; ++r) {
    const float ir = __shfl(inv, (lane & 48) | (q4 * 4 + r));
    const int trow = q0 + wid * 16 + q4 * 4 + r;
    const size_t ro = ((size_t)b * 2048 + trow) * 1024 + h * 64;
#pragma unroll
    for (int fn = 0; fn < 4; ++fn)
      ctx[ro + fn * 16 + l15] = f2b(oacc[fn][r] * ir);
  }
}

extern "C" void kernel_launch(void* const* d_in, const int* in_sizes, int n_in,
                              void* d_out, int out_size, void* d_ws, size_t ws_size,
                              hipStream_t stream) {
  const float* x  = (const float*)d_in[0];
  const float* wq = (const float*)d_in[1];
  const float* bq = (const float*)d_in[2];
  const float* wk = (const float*)d_in[3];
  const float* bk = (const float*)d_in[4];
  const float* wv = (const float*)d_in[5];
  const float* bv = (const float*)d_in[6];
  const float* wo = (const float*)d_in[7];
  const float* bo = (const float*)d_in[8];
  // d_in[9]/d_in[10] (rot tables) unused: constant-angle RoPE cancels in q.k^T.

  char* ws = (char*)d_ws;
  unsigned short* xb  = (unsigned short*)(ws);               // 8 MB (reused as ctx)
  unsigned short* wqb = (unsigned short*)(ws + 8388608);
  unsigned short* wkb = (unsigned short*)(ws + 10485760);
  unsigned short* wvb = (unsigned short*)(ws + 12582912);
  unsigned short* wob = (unsigned short*)(ws + 14680064);
  unsigned short* Qb  = (unsigned short*)(ws + 16777216);    // 8 MB
  unsigned short* Kb  = (unsigned short*)(ws + 25165824);    // 8 MB
  unsigned short* VTb = (unsigned short*)(ws + 33554432);    // 8 MB, head-transposed V
  unsigned short* ctx = xb;  // x dead after QKV projection

  cvt_kernel<<<4096, 256, 0, stream>>>(x, xb, 1048576);
  cvt4_kernel<<<dim3(1024, 4), 256, 0, stream>>>(wq, wk, wv, wo,
                                                 wqb, wkb, wvb, wob, 262144);

  gemm_bt<0><<<dim3(32, 8, 3), 256, 0, stream>>>(
      xb, wqb, wkb, wvb, bq, bk, bv, Qb, Kb, VTb, nullptr, 4096, 1024, 1024);

  attn_kernel<<<dim3(512), dim3(512), 0, stream>>>(Qb, Kb, VTb, ctx);

  gemm_bt<1><<<dim3(32, 8, 1), 256, 0, stream>>>(
      ctx, wob, wob, wob, bo, bo, bo, nullptr, nullptr, nullptr,
      (float*)d_out, 4096, 1024, 1024);
}

// Round 4
// 156.712 us; speedup vs baseline: 1.4686x; 1.0962x over previous
//
#include <hip/hip_runtime.h>
#include <hip/hip_bf16.h>
#include <stdint.h>

// MultiHeadSelfAttention (b=2,t=2048,m=1024,h=16,d=64), bf16 MFMA pipeline.
//  - reshape head-split => head h = contiguous 131072-elem slab of the per-batch
//    (2048x1024) projection, viewed [2048][64] row-major.
//  - constant-angle RoPE on q,k cancels exactly in q.k^T => skipped.

typedef __attribute__((ext_vector_type(8))) short bf16x8;
typedef bf16x8 __attribute__((may_alias)) bf16x8_a;
typedef __attribute__((ext_vector_type(4))) float f32x4;
typedef __attribute__((ext_vector_type(2))) unsigned int u32x2;
typedef u32x2 __attribute__((may_alias)) u32x2_a;

__device__ inline unsigned short f2b(float f) {
  union { float f; unsigned int u; } x; x.f = f;
  unsigned int r = x.u + 0x7fffu + ((x.u >> 16) & 1u);  // RTNE
  return (unsigned short)(r >> 16);
}

// One fused conversion kernel: blocks [0,4096) -> x, then 1024 blocks per weight.
__global__ __launch_bounds__(256) void cvt_all(
    const float* __restrict__ x,
    const float* __restrict__ w0, const float* __restrict__ w1,
    const float* __restrict__ w2, const float* __restrict__ w3,
    unsigned short* __restrict__ xb,
    unsigned short* __restrict__ o0, unsigned short* __restrict__ o1,
    unsigned short* __restrict__ o2, unsigned short* __restrict__ o3) {
  int bid = blockIdx.x;
  const float* in; unsigned short* out; int i;
  if (bid < 4096) { in = x; out = xb; i = bid * 256 + threadIdx.x; }
  else {
    int w = (bid - 4096) >> 10;
    in = (w == 0) ? w0 : (w == 1) ? w1 : (w == 2) ? w2 : w3;
    out = (w == 0) ? o0 : (w == 1) ? o1 : (w == 2) ? o2 : o3;
    i = ((bid - 4096) & 1023) * 256 + threadIdx.x;
  }
  float4 v = reinterpret_cast<const float4*>(in)[i];
  ushort4 o;
  o.x = f2b(v.x); o.y = f2b(v.y); o.z = f2b(v.z); o.w = f2b(v.w);
  reinterpret_cast<ushort4*>(out)[i] = o;
}

// C(MxN) = A(MxK) @ W(NxK)^T + bias.  128x128 tile, BK=64, 4 waves (each 64x64).
// 2-phase pipeline: dbuf LDS; per K-step {sync; stage(next->buf^1); compute(cur)}
// so next-tile global_load_lds flies under current-tile MFMA (attn-proven order).
// EPI=0: z selects {Wq,Wk,Wv}; q,k written [token][n] bf16; V written HEAD-TRANSPOSED:
//   u = t*16 + (col>>6); VT[(b*16 + (u>>11))*131072 + (col&63)*2048 + (u&2047)]
// EPI=1: fp32 output (final projection).
template<int EPI>
__global__ __launch_bounds__(256) void gemm_bt(
    const unsigned short* __restrict__ A,
    const unsigned short* __restrict__ W0, const unsigned short* __restrict__ W1,
    const unsigned short* __restrict__ W2,
    const float* __restrict__ b0, const float* __restrict__ b1, const float* __restrict__ b2,
    unsigned short* __restrict__ o0, unsigned short* __restrict__ o1,
    unsigned short* __restrict__ o2,
    float* __restrict__ of, int M, int N, int K)
{
  const int tid = threadIdx.x;
  const int lane = tid & 63;
  const int wid = tid >> 6;
  const int q4 = lane >> 4;
  const int l15 = lane & 15;
  const int wr = wid >> 1, wc = wid & 1;

  const unsigned short* W = W0; const float* bias = b0; unsigned short* ob = o0;
  if (EPI == 0) {
    if (blockIdx.z == 1) { W = W1; bias = b1; ob = o1; }
    else if (blockIdx.z == 2) { W = W2; bias = b2; ob = o2; }
  }

  __shared__ __align__(16) unsigned short sA[2][128 * 64];
  __shared__ __align__(16) unsigned short sB[2][128 * 64];
  char* sAc = (char*)sA;
  char* sBc = (char*)sB;

  f32x4 acc[4][4];
#pragma unroll
  for (int i = 0; i < 4; ++i)
#pragma unroll
    for (int j = 0; j < 4; ++j) acc[i][j] = (f32x4){0.f, 0.f, 0.f, 0.f};

  const size_t rowA0 = (size_t)blockIdx.x * 128;
  const size_t rowB0 = (size_t)blockIdx.y * 128;

  // per-lane staging source (row, inverse-swizzled chunk) for each of 4 sweeps
  auto stage = [&](int bs, int k0) {
#pragma unroll
    for (int it = 0; it < 4; ++it) {
      int Loff = it * 4096 + wid * 1024;          // wave-uniform LDS byte base
      int L = Loff + lane * 16;                   // linear LDS byte this lane fills
      int row = L >> 7;                           // tile row (128B per row)
      int csrc = ((L >> 4) & 7) ^ (row & 7);      // inverse-swizzled source chunk
      const unsigned short* ga = A + (rowA0 + row) * K + k0 + csrc * 8;
      const unsigned short* gw = W + (rowB0 + row) * K + k0 + csrc * 8;
      __builtin_amdgcn_global_load_lds((const __attribute__((address_space(1))) void*)ga,
                                       (__attribute__((address_space(3))) void*)(sAc + bs * 16384 + Loff),
                                       16, 0, 0);
      __builtin_amdgcn_global_load_lds((const __attribute__((address_space(1))) void*)gw,
                                       (__attribute__((address_space(3))) void*)(sBc + bs * 16384 + Loff),
                                       16, 0, 0);
    }
  };

  stage(0, 0);

  const int NT = K >> 6;
  for (int t = 0; t < NT; ++t) {
    const int cur = t & 1;
    __syncthreads();                 // drains tile t's loads; buf cur^1 reads done
    if (t + 1 < NT) stage(cur ^ 1, (t + 1) * 64);   // flies under compute(t)

#pragma unroll
    for (int ks = 0; ks < 2; ++ks) {
      bf16x8 af[4], bfr[4];
#pragma unroll
      for (int f = 0; f < 4; ++f) {
        int ra = wr * 64 + f * 16 + l15;
        af[f] = *(const bf16x8_a*)(sAc + cur * 16384 + ra * 128 +
                                   ((ks * 64 + q4 * 16) ^ ((ra & 7) << 4)));
        int rb = wc * 64 + f * 16 + l15;
        bfr[f] = *(const bf16x8_a*)(sBc + cur * 16384 + rb * 128 +
                                    ((ks * 64 + q4 * 16) ^ ((rb & 7) << 4)));
      }
      __builtin_amdgcn_s_setprio(1);
#pragma unroll
      for (int i = 0; i < 4; ++i)
#pragma unroll
        for (int j = 0; j < 4; ++j)
          acc[i][j] = __builtin_amdgcn_mfma_f32_16x16x32_bf16(af[i], bfr[j], acc[i][j], 0, 0, 0);
      __builtin_amdgcn_s_setprio(0);
    }
  }

#pragma unroll
  for (int i = 0; i < 4; ++i) {
    int row = (int)rowA0 + wr * 64 + i * 16 + q4 * 4;
#pragma unroll
    for (int j = 0; j < 4; ++j) {
      int col = (int)rowB0 + wc * 64 + j * 16 + l15;
      float bv = bias[col];
      if (EPI == 0 && blockIdx.z == 2) {
        // head-transposed V output
        int bb = row >> 11;
        int cb = col >> 6, dd = col & 63;
#pragma unroll
        for (int r = 0; r < 4; ++r) {
          int u = ((row + r) & 2047) * 16 + cb;      // head-seq index
          size_t a = ((size_t)(bb * 16 + (u >> 11))) * 131072 + (size_t)dd * 2048 + (u & 2047);
          ob[a] = f2b(acc[i][j][r] + bv);
        }
      } else {
#pragma unroll
        for (int r = 0; r < 4; ++r) {
          float v = acc[i][j][r] + bv;
          if (EPI == 0) ob[(size_t)(row + r) * N + col] = f2b(v);
          else          of[(size_t)(row + r) * N + col] = v;
        }
      }
    }
  }
}

// Flash attention, swapped-QK^T structure (unchanged from round 3 — verified).
__global__ __launch_bounds__(512, 4) void attn_kernel(
    const unsigned short* __restrict__ Qg,
    const unsigned short* __restrict__ Kg,
    const unsigned short* __restrict__ VTg,
    unsigned short* __restrict__ ctx)
{
  const int tid = threadIdx.x;
  const int lane = tid & 63;
  const int wid = tid >> 6;
  const int q4 = lane >> 4;
  const int l15 = lane & 15;

  // XCD-aware decode: xcd = bid&7 owns 4 whole heads -> K/VT L2-resident.
  const int bid = blockIdx.x;
  const int bh = (bid & 7) * 4 + ((bid >> 3) >> 4);
  const int qt = (bid >> 3) & 15;
  const int b = bh >> 4, h = bh & 15;
  const size_t base = (size_t)bh * 131072;
  const unsigned short* Qh = Qg + base;
  const unsigned short* Kh = Kg + base;
  const unsigned short* VTh = VTg + base;
  const int q0 = qt * 128;

  __shared__ __align__(16) unsigned short sK[2][64 * 64];   // [kv][d], XOR-swizzled
  __shared__ __align__(16) unsigned short sV[2][64 * 64];   // [d][kv-seg], XOR-swizzled
  __shared__ __align__(16) unsigned short sP[8][1152];      // per-wave P[16 q][64 kv], stride 72

  bf16x8 qf[2];
#pragma unroll
  for (int ks = 0; ks < 2; ++ks)
    qf[ks] = *(const bf16x8*)(Qh + (size_t)(q0 + wid * 16 + l15) * 64 + ks * 32 + q4 * 8);

  const int rK = tid >> 3;
  const int colK = ((tid & 7) ^ (rK & 7)) * 8;
  const unsigned short* gK = Kh + (size_t)rK * 64 + colK;      // + kv0*64
  const unsigned short* gV = VTh + (size_t)rK * 2048 + colK;   // + kv0
  char* sKc = (char*)sK;
  char* sVc = (char*)sV;
  char* sPw = (char*)sP + wid * 2304 + l15 * 144;

  auto stage = [&](int bs, int kv0) {
    __builtin_amdgcn_global_load_lds(
        (const __attribute__((address_space(1))) void*)(gK + (size_t)kv0 * 64),
        (__attribute__((address_space(3))) void*)(sKc + bs * 8192 + wid * 1024), 16, 0, 0);
    __builtin_amdgcn_global_load_lds(
        (const __attribute__((address_space(1))) void*)(gV + kv0),
        (__attribute__((address_space(3))) void*)(sVc + bs * 8192 + wid * 1024), 16, 0, 0);
  };

  f32x4 oacc[4];                       // O[q=q4*4+r][d=fn*16+l15]
#pragma unroll
  for (int fn = 0; fn < 4; ++fn) oacc[fn] = (f32x4){0.f, 0.f, 0.f, 0.f};
  float m_run = -INFINITY, l_run = 0.f;  // softmax state for q-row = l15

  stage(0, 0);

  for (int t = 0; t < 32; ++t) {
    const int cur = t & 1;
    __syncthreads();                   // drains vmcnt: tile t staged; buf cur^1 free
    if (t < 31) stage(cur ^ 1, (t + 1) * 64);

    // ---- S^T = K Q^T : sc[fm][r] = S[kv=fm*16+q4*4+r][q=l15]
    f32x4 sc[4];
#pragma unroll
    for (int fm = 0; fm < 4; ++fm) sc[fm] = (f32x4){0.f, 0.f, 0.f, 0.f};
    __builtin_amdgcn_s_setprio(1);
#pragma unroll
    for (int ks = 0; ks < 2; ++ks) {
#pragma unroll
      for (int fm = 0; fm < 4; ++fm) {
        const int rk = fm * 16 + l15;
        bf16x8_a kf = *(const bf16x8_a*)(sKc + cur * 8192 + rk * 128 +
                                         ((ks * 64 + q4 * 16) ^ ((rk & 7) << 4)));
        sc[fm] = __builtin_amdgcn_mfma_f32_16x16x32_bf16(kf, qf[ks], sc[fm], 0, 0, 0);
      }
    }
    __builtin_amdgcn_s_setprio(0);

    // ---- online softmax: 16 local values + 2 cross-q4 shuffles
    float mx = -INFINITY;
#pragma unroll
    for (int fm = 0; fm < 4; ++fm)
#pragma unroll
      for (int r = 0; r < 4; ++r) {
        sc[fm][r] *= 0.125f;           // 1/sqrt(64)
        mx = fmaxf(mx, sc[fm][r]);
      }
    mx = fmaxf(mx, __shfl_xor(mx, 16));
    mx = fmaxf(mx, __shfl_xor(mx, 32));
    const float mnew = fmaxf(m_run, mx);
    const float sc_o = __expf(m_run - mnew);
    float rs = 0.f;
#pragma unroll
    for (int fm = 0; fm < 4; ++fm)
#pragma unroll
      for (int r = 0; r < 4; ++r) {
        sc[fm][r] = __expf(sc[fm][r] - mnew);
        rs += sc[fm][r];
      }
    rs += __shfl_xor(rs, 16);
    rs += __shfl_xor(rs, 32);
    l_run = l_run * sc_o + rs;
    m_run = mnew;

    // ---- pack P -> sP[q=l15][kv] (4x ds_write_b64; kv = fm*16 + q4*4 + r)
#pragma unroll
    for (int fm = 0; fm < 4; ++fm) {
      u32x2 pk;
      pk[0] = (unsigned)f2b(sc[fm][0]) | ((unsigned)f2b(sc[fm][1]) << 16);
      pk[1] = (unsigned)f2b(sc[fm][2]) | ((unsigned)f2b(sc[fm][3]) << 16);
      *(u32x2_a*)(sPw + fm * 32 + q4 * 8) = pk;
    }
    // fence: cross-lane LDS exchange within the wave (writes above, reads below)
    asm volatile("s_waitcnt lgkmcnt(0)" ::: "memory");
    __builtin_amdgcn_sched_barrier(0);

    // ---- rescale O (state per q=l15; O rows q=q4*4+r -> broadcast within group)
#pragma unroll
    for (int r = 0; r < 4; ++r) {
      const float so = __shfl(sc_o, (lane & 48) | (q4 * 4 + r));
#pragma unroll
      for (int fn = 0; fn < 4; ++fn) oacc[fn][r] *= so;
    }

    // ---- O += P V : A from sP, B = VT rows (d), same swizzle as K
#pragma unroll
    for (int ks2 = 0; ks2 < 2; ++ks2) {
      bf16x8_a pfrag = *(const bf16x8_a*)(sPw + ks2 * 64 + q4 * 16);
      __builtin_amdgcn_s_setprio(1);
#pragma unroll
      for (int fn = 0; fn < 4; ++fn) {
        const int rv = fn * 16 + l15;
        bf16x8_a vf = *(const bf16x8_a*)(sVc + cur * 8192 + rv * 128 +
                                         ((ks2 * 64 + q4 * 16) ^ ((rv & 7) << 4)));
        oacc[fn] = __builtin_amdgcn_mfma_f32_16x16x32_bf16(pfrag, vf, oacc[fn], 0, 0, 0);
      }
      __builtin_amdgcn_s_setprio(0);
    }
  }

  // ---- normalize + store ctx[b, t, h*64+d]
  const float inv = 1.0f / l_run;
#pragma unroll
  for (int r = 0; r < 4; ++r) {
    const float ir = __shfl(inv, (lane & 48) | (q4 * 4 + r));
    const int trow = q0 + wid * 16 + q4 * 4 + r;
    const size_t ro = ((size_t)b * 2048 + trow) * 1024 + h * 64;
#pragma unroll
    for (int fn = 0; fn < 4; ++fn)
      ctx[ro + fn * 16 + l15] = f2b(oacc[fn][r] * ir);
  }
}

extern "C" void kernel_launch(void* const* d_in, const int* in_sizes, int n_in,
                              void* d_out, int out_size, void* d_ws, size_t ws_size,
                              hipStream_t stream) {
  const float* x  = (const float*)d_in[0];
  const float* wq = (const float*)d_in[1];
  const float* bq = (const float*)d_in[2];
  const float* wk = (const float*)d_in[3];
  const float* bk = (const float*)d_in[4];
  const float* wv = (const float*)d_in[5];
  const float* bv = (const float*)d_in[6];
  const float* wo = (const float*)d_in[7];
  const float* bo = (const float*)d_in[8];
  // d_in[9]/d_in[10] (rot tables) unused: constant-angle RoPE cancels in q.k^T.

  char* ws = (char*)d_ws;
  unsigned short* xb  = (unsigned short*)(ws);               // 8 MB (reused as ctx)
  unsigned short* wqb = (unsigned short*)(ws + 8388608);
  unsigned short* wkb = (unsigned short*)(ws + 10485760);
  unsigned short* wvb = (unsigned short*)(ws + 12582912);
  unsigned short* wob = (unsigned short*)(ws + 14680064);
  unsigned short* Qb  = (unsigned short*)(ws + 16777216);    // 8 MB
  unsigned short* Kb  = (unsigned short*)(ws + 25165824);    // 8 MB
  unsigned short* VTb = (unsigned short*)(ws + 33554432);    // 8 MB, head-transposed V
  unsigned short* ctx = xb;  // x dead after QKV projection

  cvt_all<<<8192, 256, 0, stream>>>(x, wq, wk, wv, wo, xb, wqb, wkb, wvb, wob);

  gemm_bt<0><<<dim3(32, 8, 3), 256, 0, stream>>>(
      xb, wqb, wkb, wvb, bq, bk, bv, Qb, Kb, VTb, nullptr, 4096, 1024, 1024);

  attn_kernel<<<dim3(512), dim3(512), 0, stream>>>(Qb, Kb, VTb, ctx);

  gemm_bt<1><<<dim3(32, 8, 1), 256, 0, stream>>>(
      ctx, wob, wob, wob, bo, bo, bo, nullptr, nullptr, nullptr,
      (float*)d_out, 4096, 1024, 1024);
}

// Round 5
// 151.555 us; speedup vs baseline: 1.5186x; 1.0340x over previous
//
#include <hip/hip_runtime.h>
#include <hip/hip_bf16.h>
#include <stdint.h>

// MultiHeadSelfAttention (b=2,t=2048,m=1024,h=16,d=64), bf16 MFMA pipeline.
//  - reshape head-split => head h = contiguous 131072-elem slab of the per-batch
//    (2048x1024) projection, viewed [2048][64] row-major; tok = (t&127)*16 + (n>>6).
//  - constant-angle RoPE on q,k cancels exactly in q.k^T => skipped.
//  - K and V are stored in a PERMUTED kv order kv' = (n>>6)*128 + (t&127); softmax
//    and PV are permutation-invariant as long as K and V share the ordering.
//    This makes the V^T global write contiguous (register-transposed MFMA tile).
//  - Q is pre-scaled by 0.125*log2(e) so attn softmax runs natively in exp2 domain.

typedef __attribute__((ext_vector_type(8))) short bf16x8;
typedef bf16x8 __attribute__((may_alias)) bf16x8_a;
typedef __attribute__((ext_vector_type(4))) float f32x4;
typedef __attribute__((ext_vector_type(2))) unsigned int u32x2;
typedef u32x2 __attribute__((may_alias)) u32x2_a;

__device__ inline unsigned short f2b(float f) {
  union { float f; unsigned int u; } x; x.f = f;
  unsigned int r = x.u + 0x7fffu + ((x.u >> 16) & 1u);  // RTNE
  return (unsigned short)(r >> 16);
}

// One fused conversion kernel: blocks [0,4096) -> x, then 1024 blocks per weight.
__global__ __launch_bounds__(256) void cvt_all(
    const float* __restrict__ x,
    const float* __restrict__ w0, const float* __restrict__ w1,
    const float* __restrict__ w2, const float* __restrict__ w3,
    unsigned short* __restrict__ xb,
    unsigned short* __restrict__ o0, unsigned short* __restrict__ o1,
    unsigned short* __restrict__ o2, unsigned short* __restrict__ o3) {
  int bid = blockIdx.x;
  const float* in; unsigned short* out; int i;
  if (bid < 4096) { in = x; out = xb; i = bid * 256 + threadIdx.x; }
  else {
    int w = (bid - 4096) >> 10;
    in = (w == 0) ? w0 : (w == 1) ? w1 : (w == 2) ? w2 : w3;
    out = (w == 0) ? o0 : (w == 1) ? o1 : (w == 2) ? o2 : o3;
    i = ((bid - 4096) & 1023) * 256 + threadIdx.x;
  }
  float4 v = reinterpret_cast<const float4*>(in)[i];
  ushort4 o;
  o.x = f2b(v.x); o.y = f2b(v.y); o.z = f2b(v.z); o.w = f2b(v.w);
  reinterpret_cast<ushort4*>(out)[i] = o;
}

// C(MxN) = A(MxK) @ W(NxK)^T + bias.  128x128 tile, BK=64, 4 waves (each 64x64).
// 2-phase pipeline: dbuf LDS; per K-step {sync; stage(next->buf^1); compute(cur)}.
// MODE 0: z=0 -> Q bf16 row-major, pre-scaled by 0.125*log2e;
//         z=1 -> K bf16, kv'-permuted: addr = bh*131072 + kv'*64 + d.
// MODE 2: V, MFMA operands swapped so acc holds the TRANSPOSED tile; writes
//         VT'[bh][d][kv'] with lanes contiguous in kv' (coalesced 32B segments).
// MODE 1: fp32 output (final projection), row-major.
template<int MODE>
__global__ __launch_bounds__(256) void gemm_bt(
    const unsigned short* __restrict__ A,
    const unsigned short* __restrict__ W0, const unsigned short* __restrict__ W1,
    const float* __restrict__ b0, const float* __restrict__ b1,
    unsigned short* __restrict__ o0, unsigned short* __restrict__ o1,
    float* __restrict__ of, int M, int N, int K)
{
  const int tid = threadIdx.x;
  const int lane = tid & 63;
  const int wid = tid >> 6;
  const int q4 = lane >> 4;
  const int l15 = lane & 15;
  const int wr = wid >> 1, wc = wid & 1;

  const unsigned short* W = W0; const float* bias = b0; unsigned short* ob = o0;
  if (MODE == 0 && blockIdx.z == 1) { W = W1; bias = b1; ob = o1; }

  __shared__ __align__(16) unsigned short sA[2][128 * 64];
  __shared__ __align__(16) unsigned short sB[2][128 * 64];
  char* sAc = (char*)sA;
  char* sBc = (char*)sB;

  f32x4 acc[4][4];
#pragma unroll
  for (int i = 0; i < 4; ++i)
#pragma unroll
    for (int j = 0; j < 4; ++j) acc[i][j] = (f32x4){0.f, 0.f, 0.f, 0.f};

  const size_t rowA0 = (size_t)blockIdx.x * 128;
  const size_t rowB0 = (size_t)blockIdx.y * 128;

  auto stage = [&](int bs, int k0) {
#pragma unroll
    for (int it = 0; it < 4; ++it) {
      int Loff = it * 4096 + wid * 1024;          // wave-uniform LDS byte base
      int L = Loff + lane * 16;                   // linear LDS byte this lane fills
      int row = L >> 7;                           // tile row (128B per row)
      int csrc = ((L >> 4) & 7) ^ (row & 7);      // inverse-swizzled source chunk
      const unsigned short* ga = A + (rowA0 + row) * K + k0 + csrc * 8;
      const unsigned short* gw = W + (rowB0 + row) * K + k0 + csrc * 8;
      __builtin_amdgcn_global_load_lds((const __attribute__((address_space(1))) void*)ga,
                                       (__attribute__((address_space(3))) void*)(sAc + bs * 16384 + Loff),
                                       16, 0, 0);
      __builtin_amdgcn_global_load_lds((const __attribute__((address_space(1))) void*)gw,
                                       (__attribute__((address_space(3))) void*)(sBc + bs * 16384 + Loff),
                                       16, 0, 0);
    }
  };

  stage(0, 0);

  const int NT = K >> 6;
  for (int t = 0; t < NT; ++t) {
    const int cur = t & 1;
    __syncthreads();                 // drains tile t's loads; buf cur^1 reads done
    if (t + 1 < NT) stage(cur ^ 1, (t + 1) * 64);   // flies under compute(t)

#pragma unroll
    for (int ks = 0; ks < 2; ++ks) {
      bf16x8 af[4], bfr[4];
#pragma unroll
      for (int f = 0; f < 4; ++f) {
        int ra = wr * 64 + f * 16 + l15;
        af[f] = *(const bf16x8_a*)(sAc + cur * 16384 + ra * 128 +
                                   ((ks * 64 + q4 * 16) ^ ((ra & 7) << 4)));
        int rb = wc * 64 + f * 16 + l15;
        bfr[f] = *(const bf16x8_a*)(sBc + cur * 16384 + rb * 128 +
                                    ((ks * 64 + q4 * 16) ^ ((rb & 7) << 4)));
      }
      __builtin_amdgcn_s_setprio(1);
#pragma unroll
      for (int i = 0; i < 4; ++i)
#pragma unroll
        for (int j = 0; j < 4; ++j) {
          if (MODE == 2)
            acc[i][j] = __builtin_amdgcn_mfma_f32_16x16x32_bf16(bfr[j], af[i], acc[i][j], 0, 0, 0);
          else
            acc[i][j] = __builtin_amdgcn_mfma_f32_16x16x32_bf16(af[i], bfr[j], acc[i][j], 0, 0, 0);
        }
      __builtin_amdgcn_s_setprio(0);
    }
  }

  if (MODE == 2) {
    // acc[i][j][r] = value at (t = rowA0 + wr*64 + i*16 + l15,
    //                          c = rowB0 + wc*64 + j*16 + q4*4 + r)
    const int bh = (int)rowA0 >> 7;
#pragma unroll
    for (int i = 0; i < 4; ++i) {
      const int tt = wr * 64 + i * 16 + l15;       // within-head token, 0..127
      const size_t rb = (size_t)bh * 131072 + tt;
#pragma unroll
      for (int j = 0; j < 4; ++j) {
#pragma unroll
        for (int r = 0; r < 4; ++r) {
          const int c = (int)rowB0 + wc * 64 + j * 16 + q4 * 4 + r;
          ob[rb + (size_t)(c & 63) * 2048 + (size_t)(c >> 6) * 128] = f2b(acc[i][j][r] + bias[c]);
        }
      }
    }
  } else {
#pragma unroll
    for (int i = 0; i < 4; ++i) {
      int row = (int)rowA0 + wr * 64 + i * 16 + q4 * 4;
#pragma unroll
      for (int j = 0; j < 4; ++j) {
        int col = (int)rowB0 + wc * 64 + j * 16 + l15;
        float bv = bias[col];
        if (MODE == 0 && blockIdx.z == 1) {
          // K, kv'-permuted: addr = bh*131072 + ((col>>6)*128 + (row&127))*64 + d
#pragma unroll
          for (int r = 0; r < 4; ++r) {
            size_t a = (size_t)((row + r) >> 7) * 131072 +
                       (size_t)(((col >> 6) << 7) + ((row + r) & 127)) * 64 + (col & 63);
            ob[a] = f2b(acc[i][j][r] + bv);
          }
        } else {
#pragma unroll
          for (int r = 0; r < 4; ++r) {
            float v = acc[i][j][r] + bv;
            if (MODE == 0) ob[(size_t)(row + r) * N + col] = f2b(v * 0.18033688f);  // Q: 0.125*log2e
            else           of[(size_t)(row + r) * N + col] = v;
          }
        }
      }
    }
  }
}

// Flash attention, swapped-QK^T structure. Q pre-scaled => S is in log2 domain.
// Block = 512 thr (8 waves), 128 Q rows (16/wave), KV tiles of 64, dbuf K/VT.
// S^T = mfma(K, Q): lane(q4,l15) holds S[kv=fm*16+q4*4+r][q=l15] -> row softmax
// in 2 shfl_xor. Defer-max (T13): skip O-rescale when max growth <= 11.54 (=8/ln2).
__global__ __launch_bounds__(512, 4) void attn_kernel(
    const unsigned short* __restrict__ Qg,
    const unsigned short* __restrict__ Kg,
    const unsigned short* __restrict__ VTg,
    unsigned short* __restrict__ ctx)
{
  const int tid = threadIdx.x;
  const int lane = tid & 63;
  const int wid = tid >> 6;
  const int q4 = lane >> 4;
  const int l15 = lane & 15;

  // XCD-aware decode: xcd = bid&7 owns 4 whole heads -> K/VT L2-resident.
  const int bid = blockIdx.x;
  const int bh = (bid & 7) * 4 + ((bid >> 3) >> 4);
  const int qt = (bid >> 3) & 15;
  const int b = bh >> 4, h = bh & 15;
  const size_t base = (size_t)bh * 131072;
  const unsigned short* Qh = Qg + base;
  const unsigned short* Kh = Kg + base;
  const unsigned short* VTh = VTg + base;
  const int q0 = qt * 128;

  __shared__ __align__(16) unsigned short sK[2][64 * 64];   // [kv'][d], XOR-swizzled
  __shared__ __align__(16) unsigned short sV[2][64 * 64];   // [d][kv'-seg], XOR-swizzled
  __shared__ __align__(16) unsigned short sP[8][1152];      // per-wave P[16 q][64 kv], stride 72

  bf16x8 qf[2];
#pragma unroll
  for (int ks = 0; ks < 2; ++ks)
    qf[ks] = *(const bf16x8*)(Qh + (size_t)(q0 + wid * 16 + l15) * 64 + ks * 32 + q4 * 8);

  const int rK = tid >> 3;
  const int colK = ((tid & 7) ^ (rK & 7)) * 8;
  const unsigned short* gK = Kh + (size_t)rK * 64 + colK;      // + kv0*64
  const unsigned short* gV = VTh + (size_t)rK * 2048 + colK;   // + kv0
  char* sKc = (char*)sK;
  char* sVc = (char*)sV;
  char* sPw = (char*)sP + wid * 2304 + l15 * 144;

  auto stage = [&](int bs, int kv0) {
    __builtin_amdgcn_global_load_lds(
        (const __attribute__((address_space(1))) void*)(gK + (size_t)kv0 * 64),
        (__attribute__((address_space(3))) void*)(sKc + bs * 8192 + wid * 1024), 16, 0, 0);
    __builtin_amdgcn_global_load_lds(
        (const __attribute__((address_space(1))) void*)(gV + kv0),
        (__attribute__((address_space(3))) void*)(sVc + bs * 8192 + wid * 1024), 16, 0, 0);
  };

  f32x4 oacc[4];                       // O[q=q4*4+r][d=fn*16+l15]
#pragma unroll
  for (int fn = 0; fn < 4; ++fn) oacc[fn] = (f32x4){0.f, 0.f, 0.f, 0.f};
  float m_run = -INFINITY, l_run = 0.f;  // log2-domain softmax state for q-row = l15

  stage(0, 0);

  for (int t = 0; t < 32; ++t) {
    const int cur = t & 1;
    __syncthreads();                   // drains vmcnt: tile t staged; buf cur^1 free
    if (t < 31) stage(cur ^ 1, (t + 1) * 64);

    // ---- S^T = K Q^T : sc[fm][r] = S_log2[kv=fm*16+q4*4+r][q=l15]
    f32x4 sc[4];
#pragma unroll
    for (int fm = 0; fm < 4; ++fm) sc[fm] = (f32x4){0.f, 0.f, 0.f, 0.f};
    __builtin_amdgcn_s_setprio(1);
#pragma unroll
    for (int ks = 0; ks < 2; ++ks) {
#pragma unroll
      for (int fm = 0; fm < 4; ++fm) {
        const int rk = fm * 16 + l15;
        bf16x8_a kf = *(const bf16x8_a*)(sKc + cur * 8192 + rk * 128 +
                                         ((ks * 64 + q4 * 16) ^ ((rk & 7) << 4)));
        sc[fm] = __builtin_amdgcn_mfma_f32_16x16x32_bf16(kf, qf[ks], sc[fm], 0, 0, 0);
      }
    }
    __builtin_amdgcn_s_setprio(0);

    // ---- online softmax (exp2 domain, defer-max): 15 fmax + 2 shfl
    float mx = fmaxf(fmaxf(fmaxf(sc[0][0], sc[0][1]), fmaxf(sc[0][2], sc[0][3])),
                     fmaxf(fmaxf(sc[1][0], sc[1][1]), fmaxf(sc[1][2], sc[1][3])));
    mx = fmaxf(mx, fmaxf(fmaxf(fmaxf(sc[2][0], sc[2][1]), fmaxf(sc[2][2], sc[2][3])),
                         fmaxf(fmaxf(sc[3][0], sc[3][1]), fmaxf(sc[3][2], sc[3][3]))));
    mx = fmaxf(mx, __shfl_xor(mx, 16));
    mx = fmaxf(mx, __shfl_xor(mx, 32));
    if (!__all(mx <= m_run + 11.54f)) {      // wave-uniform rescale path
      const float mnew = fmaxf(m_run, mx);
      const float sc_o = exp2f(m_run - mnew);   // m_run=-inf on t=0 -> 0
      l_run *= sc_o;
      m_run = mnew;
#pragma unroll
      for (int r = 0; r < 4; ++r) {
        const float so = __shfl(sc_o, (lane & 48) | (q4 * 4 + r));
#pragma unroll
        for (int fn = 0; fn < 4; ++fn) oacc[fn][r] *= so;
      }
    }
    float rs = 0.f;
#pragma unroll
    for (int fm = 0; fm < 4; ++fm)
#pragma unroll
      for (int r = 0; r < 4; ++r) {
        sc[fm][r] = exp2f(sc[fm][r] - m_run);   // bounded by 2^11.54
        rs += sc[fm][r];
      }
    rs += __shfl_xor(rs, 16);
    rs += __shfl_xor(rs, 32);
    l_run += rs;

    // ---- pack P -> sP[q=l15][kv] (4x ds_write_b64; kv = fm*16 + q4*4 + r)
#pragma unroll
    for (int fm = 0; fm < 4; ++fm) {
      u32x2 pk;
      pk[0] = (unsigned)f2b(sc[fm][0]) | ((unsigned)f2b(sc[fm][1]) << 16);
      pk[1] = (unsigned)f2b(sc[fm][2]) | ((unsigned)f2b(sc[fm][3]) << 16);
      *(u32x2_a*)(sPw + fm * 32 + q4 * 8) = pk;
    }
    // fence: cross-lane LDS exchange within the wave (writes above, reads below)
    asm volatile("s_waitcnt lgkmcnt(0)" ::: "memory");
    __builtin_amdgcn_sched_barrier(0);

    // ---- O += P V : A from sP, B = VT rows (d), same swizzle as K
#pragma unroll
    for (int ks2 = 0; ks2 < 2; ++ks2) {
      bf16x8_a pfrag = *(const bf16x8_a*)(sPw + ks2 * 64 + q4 * 16);
      __builtin_amdgcn_s_setprio(1);
#pragma unroll
      for (int fn = 0; fn < 4; ++fn) {
        const int rv = fn * 16 + l15;
        bf16x8_a vf = *(const bf16x8_a*)(sVc + cur * 8192 + rv * 128 +
                                         ((ks2 * 64 + q4 * 16) ^ ((rv & 7) << 4)));
        oacc[fn] = __builtin_amdgcn_mfma_f32_16x16x32_bf16(pfrag, vf, oacc[fn], 0, 0, 0);
      }
      __builtin_amdgcn_s_setprio(0);
    }
  }

  // ---- normalize + store ctx[b, t, h*64+d]
  const float inv = 1.0f / l_run;
#pragma unroll
  for (int r = 0; r < 4; ++r) {
    const float ir = __shfl(inv, (lane & 48) | (q4 * 4 + r));
    const int trow = q0 + wid * 16 + q4 * 4 + r;
    const size_t ro = ((size_t)b * 2048 + trow) * 1024 + h * 64;
#pragma unroll
    for (int fn = 0; fn < 4; ++fn)
      ctx[ro + fn * 16 + l15] = f2b(oacc[fn][r] * ir);
  }
}

extern "C" void kernel_launch(void* const* d_in, const int* in_sizes, int n_in,
                              void* d_out, int out_size, void* d_ws, size_t ws_size,
                              hipStream_t stream) {
  const float* x  = (const float*)d_in[0];
  const float* wq = (const float*)d_in[1];
  const float* bq = (const float*)d_in[2];
  const float* wk = (const float*)d_in[3];
  const float* bk = (const float*)d_in[4];
  const float* wv = (const float*)d_in[5];
  const float* bv = (const float*)d_in[6];
  const float* wo = (const float*)d_in[7];
  const float* bo = (const float*)d_in[8];
  // d_in[9]/d_in[10] (rot tables) unused: constant-angle RoPE cancels in q.k^T.

  char* ws = (char*)d_ws;
  unsigned short* xb  = (unsigned short*)(ws);               // 8 MB (reused as ctx)
  unsigned short* wqb = (unsigned short*)(ws + 8388608);
  unsigned short* wkb = (unsigned short*)(ws + 10485760);
  unsigned short* wvb = (unsigned short*)(ws + 12582912);
  unsigned short* wob = (unsigned short*)(ws + 14680064);
  unsigned short* Qb  = (unsigned short*)(ws + 16777216);    // 8 MB
  unsigned short* Kb  = (unsigned short*)(ws + 25165824);    // 8 MB, kv'-permuted
  unsigned short* VTb = (unsigned short*)(ws + 33554432);    // 8 MB, [bh][d][kv']
  unsigned short* ctx = xb;  // x dead after QKV projection

  cvt_all<<<8192, 256, 0, stream>>>(x, wq, wk, wv, wo, xb, wqb, wkb, wvb, wob);

  gemm_bt<0><<<dim3(32, 8, 2), 256, 0, stream>>>(
      xb, wqb, wkb, bq, bk, Qb, Kb, nullptr, 4096, 1024, 1024);
  gemm_bt<2><<<dim3(32, 8, 1), 256, 0, stream>>>(
      xb, wvb, nullptr, bv, nullptr, VTb, nullptr, nullptr, 4096, 1024, 1024);

  attn_kernel<<<dim3(512), dim3(512), 0, stream>>>(Qb, Kb, VTb, ctx);

  gemm_bt<1><<<dim3(32, 8, 1), 256, 0, stream>>>(
      ctx, wob, nullptr, bo, nullptr, nullptr, nullptr,
      (float*)d_out, 4096, 1024, 1024);
}